// Round 1
// 122.582 us; speedup vs baseline: 1.0180x; 1.0180x over previous
//
#include <hip/hip_runtime.h>
#include <stdint.h>

// Problem constants (fixed by the reference)
#define B_      16
#define N_      2048
#define M_      8192
#define ROWS    (B_ * N_)        // 32768
#define D_      8                // 4*2 flattened

// Kernel A tiling
#define SPLITS  32               // anchor splits
#define MSPLIT  (M_ / SPLITS)    // 256 anchors per split
#define BLK     256              // threads per block
#define RPT     8                // rows per thread
#define ROWS_PER_BLK (BLK * RPT) // 2048
#define ROWBLKS (ROWS / ROWS_PER_BLK) // 16  -> grid 16x32 = 512 blocks

// Kernel B tiling
#define TPR     8                // threads per row
#define BROWS   32               // rows per block (256 threads)

typedef float f32x2 __attribute__((ext_vector_type(2)));

// ws: float[SPLITS][ROWS] per-(split,row) min score = 4 MB. Every slot written
// by kernel A (no init, no atomics).

// Kernel A: per (row, split) min score via packed FP32.
//  - __launch_bounds__(BLK,2): 128-VGPR cap (grid is exactly 2 blocks/CU).
//    The previous build's bare launch_bounds gave VGPR_Count=56 < the 64
//    floats of X -> X lived in AGPRs, and ~64 v_accvgpr_read per j-iter
//    doubled VALU issue (66 us vs 30.7 us scalar floor, VALUBusy 93%).
//  - v_pk_fma_f32 processes TWO ROWS per instruction. Anchors staged in LDS
//    duplicated ({-a,-a}) so the packed addend/operands need no lane movs.
//    Per-anchor, per-2-rows: 8 pk_fma + 2 fmin = 5 VALU instr/pair (vs 9).
//  - Each row's chain is fma(x0,-a0,hn), fma(x1,-a1,.), ... ascending dims,
//    ascending j — BIT-IDENTICAL to the old kernel and to kernel B's rescan
//    chain, so ws (and the final output) is bit-exact vs the passing build.
__global__ __launch_bounds__(BLK, 2) void argmin_part_kernel(
    const float* __restrict__ x,        // [ROWS][8]
    const float* __restrict__ anchors,  // [M_][8]
    float* __restrict__ ws)             // [SPLITS][ROWS]
{
    __shared__ f32x2 sA2[MSPLIT * D_];  // 16 KB: negated anchors, duplicated
    __shared__ f32x2 sH2[MSPLIT];       //  2 KB: {0.5*||a||^2, same}

    const int split = blockIdx.y;
    const int tid   = threadIdx.x;

    // Stage: thread j owns anchor j (BLK == MSPLIT). One-time cost; the
    // 64B-stride LDS writes bank-conflict but it's ~500 cycles once.
    {
        const float4* gA = (const float4*)(anchors + (size_t)(split * MSPLIT + tid) * D_);
        const float4 g0 = gA[0], g1 = gA[1];
        float na[8];
        na[0] = -g0.x; na[1] = -g0.y; na[2] = -g0.z; na[3] = -g0.w;
        na[4] = -g1.x; na[5] = -g1.y; na[6] = -g1.z; na[7] = -g1.w;
        #pragma unroll
        for (int k = 0; k < 8; ++k) {
            f32x2 d; d.x = na[k]; d.y = na[k];
            sA2[tid * D_ + k] = d;
        }
        // Half-norm: EXACT chain replicated in kernel B ((-a)*(-a)==a*a bitwise)
        float nr = na[0] * na[0];
        #pragma unroll
        for (int k = 1; k < 8; ++k) nr = fmaf(na[k], na[k], nr);
        f32x2 h; h.x = 0.5f * nr; h.y = h.x;
        sH2[tid] = h;
    }
    __syncthreads();

    // My 8 rows, packed as 4 row-pairs: P[p][k] = {row(2p)[k], row(2p+1)[k]}
    const int row0 = blockIdx.x * ROWS_PER_BLK + tid;
    f32x2 P[4][8];
    #pragma unroll
    for (int p = 0; p < 4; ++p) {
        const float4* pa = (const float4*)(x + (size_t)(row0 + (2 * p) * BLK) * D_);
        const float4* pb = (const float4*)(x + (size_t)(row0 + (2 * p + 1) * BLK) * D_);
        const float4 a0 = pa[0], a1 = pa[1];
        const float4 b0 = pb[0], b1 = pb[1];
        P[p][0].x = a0.x; P[p][0].y = b0.x;
        P[p][1].x = a0.y; P[p][1].y = b0.y;
        P[p][2].x = a0.z; P[p][2].y = b0.z;
        P[p][3].x = a0.w; P[p][3].y = b0.w;
        P[p][4].x = a1.x; P[p][4].y = b1.x;
        P[p][5].x = a1.y; P[p][5].y = b1.y;
        P[p][6].x = a1.z; P[p][6].y = b1.z;
        P[p][7].x = a1.w; P[p][7].y = b1.w;
    }

    f32x2 best[4];
    #pragma unroll
    for (int p = 0; p < 4; ++p) { best[p].x = 3.4e38f; best[p].y = 3.4e38f; }

    #pragma unroll 2
    for (int j = 0; j < MSPLIT; ++j) {
        const f32x2* aj = &sA2[j * D_];
        const f32x2 A0 = aj[0], A1 = aj[1], A2 = aj[2], A3 = aj[3];
        const f32x2 A4 = aj[4], A5 = aj[5], A6 = aj[6], A7 = aj[7];
        const f32x2 hn2 = sH2[j];
        #pragma unroll
        for (int p = 0; p < 4; ++p) {
            f32x2 s;
            // lane l: s = hn + x0*(-a0); then += xk*(-ak) ascending k.
            asm("v_pk_fma_f32 %0, %1, %2, %3" : "=v"(s) : "v"(P[p][0]), "v"(A0), "v"(hn2));
            asm("v_pk_fma_f32 %0, %1, %2, %0" : "+v"(s) : "v"(P[p][1]), "v"(A1));
            asm("v_pk_fma_f32 %0, %1, %2, %0" : "+v"(s) : "v"(P[p][2]), "v"(A2));
            asm("v_pk_fma_f32 %0, %1, %2, %0" : "+v"(s) : "v"(P[p][3]), "v"(A3));
            asm("v_pk_fma_f32 %0, %1, %2, %0" : "+v"(s) : "v"(P[p][4]), "v"(A4));
            asm("v_pk_fma_f32 %0, %1, %2, %0" : "+v"(s) : "v"(P[p][5]), "v"(A5));
            asm("v_pk_fma_f32 %0, %1, %2, %0" : "+v"(s) : "v"(P[p][6]), "v"(A6));
            asm("v_pk_fma_f32 %0, %1, %2, %0" : "+v"(s) : "v"(P[p][7]), "v"(A7));
            best[p].x = fminf(best[p].x, s.x);
            best[p].y = fminf(best[p].y, s.y);
        }
    }

    #pragma unroll
    for (int p = 0; p < 4; ++p) {
        ws[(size_t)split * ROWS + (row0 + (2 * p) * BLK)]     = best[p].x;   // coalesced
        ws[(size_t)split * ROWS + (row0 + (2 * p + 1) * BLK)] = best[p].y;
    }
}

// Kernel B: 8 threads per row. Phase 1: reduce 32 split-minima -> winning
// (value, split) with lowest-split tie-break (== ascending strict '<').
// Phase 2: the 8 threads rescan the winning split (32 anchors each, lane-
// strided so 8 consecutive lanes read 8 consecutive anchors) with the
// bit-identical fmaf chain; min global index among bit-exact matches ==
// first occurrence == jnp.argmin tie-break. Phase 3: fused q_sample output.
__global__ __launch_bounds__(256) void refine_combine_kernel(
    const float* __restrict__ x,        // [ROWS][8]
    const float* __restrict__ anchors,  // [M_][8]
    const float* __restrict__ sa_tab,   // [1000]
    const float* __restrict__ sb_tab,   // [1000]
    const int*   __restrict__ t,        // [B_]
    const float* __restrict__ ws,       // [SPLITS][ROWS]
    float* __restrict__ out)            // [ROWS][8]
{
    const int tid  = threadIdx.x;
    const int g    = tid & (TPR - 1);   // lane within row-group
    const int rloc = tid >> 3;
    const int row  = blockIdx.x * BROWS + rloc;

    // Phase 1: per-thread scan of splits g, g+8, g+16, g+24 (ascending ->
    // strict '<' keeps lowest split within thread)
    float bs = 3.4e38f;
    int bsplit = 0;
    #pragma unroll
    for (int k = 0; k < SPLITS / TPR; ++k) {
        const int s = g + k * TPR;
        const float v = ws[(size_t)s * ROWS + row];
        const bool c = v < bs;
        bs     = c ? v : bs;
        bsplit = c ? s : bsplit;
    }
    // Cross-lane tuple-min over the 8-lane group (xor masks stay in-group)
    #pragma unroll
    for (int m = 1; m < TPR; m <<= 1) {
        const float ov  = __shfl_xor(bs, m);
        const int   osp = __shfl_xor(bsplit, m);
        const bool take = (ov < bs) || (ov == bs && osp < bsplit);
        bs     = take ? ov  : bs;
        bsplit = take ? osp : bsplit;
    }
    const uint32_t target = __float_as_uint(bs);
    const int base = bsplit * MSPLIT;

    // My row
    const float4* px = (const float4*)(x + (size_t)row * D_);
    const float4 xlo = px[0], xhi = px[1];
    const float X0 = xlo.x, X1 = xlo.y, X2 = xlo.z, X3 = xlo.w;
    const float X4 = xhi.x, X5 = xhi.y, X6 = xhi.z, X7 = xhi.w;

    // Phase 2: rescan winning split, lane-strided (coalesced within row-group)
    int mloc = 0x7FFFFFFF;
    #pragma unroll 4
    for (int j = 0; j < MSPLIT / TPR; ++j) {
        const int ai = base + j * TPR + g;
        const float4* pa = (const float4*)(anchors + (size_t)ai * D_);
        const float4 g0 = pa[0], g1 = pa[1];
        const float na0 = -g0.x, na1 = -g0.y, na2 = -g0.z, na3 = -g0.w;
        const float na4 = -g1.x, na5 = -g1.y, na6 = -g1.z, na7 = -g1.w;
        // hn chain — bit-identical to kernel A
        float nr = na0 * na0;
        nr = fmaf(na1, na1, nr);
        nr = fmaf(na2, na2, nr);
        nr = fmaf(na3, na3, nr);
        nr = fmaf(na4, na4, nr);
        nr = fmaf(na5, na5, nr);
        nr = fmaf(na6, na6, nr);
        nr = fmaf(na7, na7, nr);
        const float hn = 0.5f * nr;
        // score chain — bit-identical to kernel A
        float s = fmaf(X0, na0, hn);
        s = fmaf(X1, na1, s);
        s = fmaf(X2, na2, s);
        s = fmaf(X3, na3, s);
        s = fmaf(X4, na4, s);
        s = fmaf(X5, na5, s);
        s = fmaf(X6, na6, s);
        s = fmaf(X7, na7, s);
        const bool m = (__float_as_uint(s) == target);
        mloc = (m && ai < mloc) ? ai : mloc;   // ai ascending in j -> min = first
    }
    #pragma unroll
    for (int m = 1; m < TPR; m <<= 1) {
        const int o = __shfl_xor(mloc, m);
        mloc = (o < mloc) ? o : mloc;
    }
    const int bi = (mloc == 0x7FFFFFFF) ? base : mloc;  // defensive (cannot happen)

    // Phase 3: one lane per row writes the fused output
    if (g == 0) {
        const int b  = row >> 11;               // row / N_
        const int tb = t[b];
        const float sa = sa_tab[tb];
        const float sb = sb_tab[tb];

        const float4* pa = (const float4*)(anchors + (size_t)bi * D_);
        const float4 a0 = pa[0], a1 = pa[1];

        float4 o0, o1;
        o0.x = fmaf(sa, xlo.x, sb * a0.x);
        o0.y = fmaf(sa, xlo.y, sb * a0.y);
        o0.z = fmaf(sa, xlo.z, sb * a0.z);
        o0.w = fmaf(sa, xlo.w, sb * a0.w);
        o1.x = fmaf(sa, xhi.x, sb * a1.x);
        o1.y = fmaf(sa, xhi.y, sb * a1.y);
        o1.z = fmaf(sa, xhi.z, sb * a1.z);
        o1.w = fmaf(sa, xhi.w, sb * a1.w);

        float4* po = (float4*)(out + (size_t)row * D_);
        po[0] = o0;
        po[1] = o1;
    }
}

extern "C" void kernel_launch(void* const* d_in, const int* in_sizes, int n_in,
                              void* d_out, int out_size, void* d_ws, size_t ws_size,
                              hipStream_t stream) {
    const float* x       = (const float*)d_in[0];  // x_start [16,2048,4,2]
    const float* anchors = (const float*)d_in[1];  // anchors [8192,4,2]
    const float* sa_tab  = (const float*)d_in[2];  // sqrt_alphas_cumprod [1000]
    const float* sb_tab  = (const float*)d_in[3];  // sqrt_one_minus_alphas_cumprod [1000]
    const int*   t       = (const int*)d_in[4];    // t [16]
    float* out = (float*)d_out;

    float* ws = (float*)d_ws;   // [SPLITS][ROWS] = 4 MB, fully overwritten

    dim3 gridA(ROWBLKS, SPLITS);   // 16 x 32 = 512 blocks
    argmin_part_kernel<<<gridA, BLK, 0, stream>>>(x, anchors, ws);

    refine_combine_kernel<<<ROWS / BROWS, 256, 0, stream>>>(
        x, anchors, sa_tab, sb_tab, t, ws, out);
}